// Round 1
// baseline (168.632 us; speedup 1.0000x reference)
//
#include <hip/hip_runtime.h>
#include <math.h>

#ifndef __has_builtin
#define __has_builtin(x) 0
#endif

#if __has_builtin(__builtin_amdgcn_exp2f)
#define EXP2F(x) __builtin_amdgcn_exp2f(x)
#else
#define EXP2F(x) exp2f(x)
#endif

#if __has_builtin(__builtin_amdgcn_logf)
#define LOG2F(x) __builtin_amdgcn_logf(x)
#else
#define LOG2F(x) log2f(x)
#endif

#define LOG2E 1.4426950408889634f
#define LN2   0.6931471805599453f

// ds_swizzle broadcast within each 32-lane group: src = ((lane&0)|J)^0 = J
#define SWZ(v, J) __int_as_float(__builtin_amdgcn_ds_swizzle(__float_as_int(v), ((J) << 5)))

#define REP32(M) \
  M(0) M(1) M(2) M(3) M(4) M(5) M(6) M(7) \
  M(8) M(9) M(10) M(11) M(12) M(13) M(14) M(15) \
  M(16) M(17) M(18) M(19) M(20) M(21) M(22) M(23) \
  M(24) M(25) M(26) M(27) M(28) M(29) M(30) M(31)

// softmin_i(eps, h) = -eps * log( sum_j exp(h[j] - C[i,j]/eps) ), stabilized.
// Lane owns row i: Crow[j] = C[i,j] (registers). h is this lane's own h[i];
// h[j] obtained via ds_swizzle broadcast (both 32-lane halves = 2 batches/wave).
__device__ __forceinline__ float softmin32(float eps, float inv_eps,
                                           const float Crow[32], float h) {
  float arg[32];
  float mx[4] = {-3.4e38f, -3.4e38f, -3.4e38f, -3.4e38f};
#define SM_ARG(J) { float hj = SWZ(h, J); arg[J] = fmaf(Crow[J], -inv_eps, hj); \
                    mx[(J) & 3] = fmaxf(mx[(J) & 3], arg[J]); }
  REP32(SM_ARG)
#undef SM_ARG
  float m = fmaxf(fmaxf(mx[0], mx[1]), fmaxf(mx[2], mx[3]));
  float nml = m * LOG2E;
  float s[4] = {0.f, 0.f, 0.f, 0.f};
#define SM_EXP(J) s[(J) & 3] += EXP2F(fmaf(arg[J], LOG2E, -nml));
  REP32(SM_EXP)
#undef SM_EXP
  float ssum = (s[0] + s[1]) + (s[2] + s[3]);
  return -eps * fmaf(LOG2F(ssum), LN2, m);
}

__global__ __launch_bounds__(256) void sink_kernel(
    const float* __restrict__ pred, const float* __restrict__ tgt,
    const float* __restrict__ pos, float* __restrict__ ws) {
  const int tid  = blockIdx.x * 256 + threadIdx.x;
  const int lane = threadIdx.x & 31;   // point index i within the batch

  const float p  = pred[tid];
  const float tg = tgt[tid];
  const float al = LOG2F(p)  * LN2;    // log(pred)
  const float bl = LOG2F(tg) * LN2;    // log(target)

  // C row for this lane: C[i,j] = 0.5*||x_i - x_j||^2, positions shared.
  const float xi = pos[2 * lane], yi = pos[2 * lane + 1];
  float Crow[32];
#define CPOS(J) { float xj = SWZ(xi, J), yj = SWZ(yi, J); \
                  float dx = xi - xj, dy = yi - yj; \
                  Crow[J] = 0.5f * (dx * dx + dy * dy); }
  REP32(CPOS)
#undef CPOS

  // eps schedule: [8, 8, 2, 0.5, 0.125, 0.03125, 0.01]; damp = 1/(1+eps)
  const float EPSV[7] = {8.f, 8.f, 2.f, 0.5f, 0.125f, 0.03125f, 0.01f};
  const float INVV[7] = {0.125f, 0.125f, 0.5f, 2.f, 8.f, 32.f, 100.f};
  const float DMPV[7] = {1.f/9.f, 1.f/9.f, 1.f/3.f, 2.f/3.f, 8.f/9.f, 32.f/33.f, 100.f/101.f};

  // init at eps0=8: g_ab = f_aa = d0*softmin(a_log); f_ba = g_bb = d0*softmin(b_log)
  const float d0  = 1.f / 9.f;
  const float sma = softmin32(8.f, 0.125f, Crow, al);
  const float smb = softmin32(8.f, 0.125f, Crow, bl);
  float g_ab = d0 * sma, f_aa = d0 * sma;
  float f_ba = d0 * smb, g_bb = d0 * smb;

  // 7 annealing iterations (averaged updates) + 1 final extrapolation (assign)
#pragma unroll 1
  for (int k = 0; k < 8; ++k) {
    const int   e   = (k < 7) ? k : 6;
    const float eps = EPSV[e], inv = INVV[e], d = DMPV[e];
    const float ft = d * softmin32(eps, inv, Crow, fmaf(g_ab, inv, bl));
    const float gt = d * softmin32(eps, inv, Crow, fmaf(f_ba, inv, al));
    const float fa = d * softmin32(eps, inv, Crow, fmaf(f_aa, inv, al));
    const float gb = d * softmin32(eps, inv, Crow, fmaf(g_bb, inv, bl));
    if (k < 7) {
      f_ba = 0.5f * (f_ba + ft); g_ab = 0.5f * (g_ab + gt);
      f_aa = 0.5f * (f_aa + fa); g_bb = 0.5f * (g_bb + gb);
    } else {
      f_ba = ft; g_ab = gt; f_aa = fa; g_bb = gb;
    }
  }

  // per-lane debiased unbalanced cost contribution (RHO = 1)
  float c = p  * (EXP2F(-f_aa * LOG2E) - EXP2F(-f_ba * LOG2E))
          + tg * (EXP2F(-g_bb * LOG2E) - EXP2F(-g_ab * LOG2E));

  // reduce over 32 lanes (xor offsets <=16 stay within each half-wave)
  c += __shfl_xor(c, 16);
  c += __shfl_xor(c, 8);
  c += __shfl_xor(c, 4);
  c += __shfl_xor(c, 2);
  c += __shfl_xor(c, 1);

  __shared__ float bsum[8];
  if (lane == 0) bsum[threadIdx.x >> 5] = c;
  __syncthreads();
  if (threadIdx.x == 0) {
    float t = 0.f;
#pragma unroll
    for (int g = 0; g < 8; ++g) t += bsum[g];
    ws[blockIdx.x] = t;
  }
}

__global__ __launch_bounds__(256) void reduce_kernel(
    const float* __restrict__ ws, float* __restrict__ out, int n, float scale) {
  float s = 0.f;
  for (int i = threadIdx.x; i < n; i += 256) s += ws[i];
  s += __shfl_xor(s, 32);
  s += __shfl_xor(s, 16);
  s += __shfl_xor(s, 8);
  s += __shfl_xor(s, 4);
  s += __shfl_xor(s, 2);
  s += __shfl_xor(s, 1);
  __shared__ float a[4];
  if ((threadIdx.x & 63) == 0) a[threadIdx.x >> 6] = s;
  __syncthreads();
  if (threadIdx.x == 0) out[0] = ((a[0] + a[1]) + (a[2] + a[3])) * scale;
}

extern "C" void kernel_launch(void* const* d_in, const int* in_sizes, int n_in,
                              void* d_out, int out_size, void* d_ws, size_t ws_size,
                              hipStream_t stream) {
  const float* pred = (const float*)d_in[0];
  const float* tgt  = (const float*)d_in[1];
  const float* pos  = (const float*)d_in[2];
  const int B = in_sizes[0] / 32;        // 32768 batches
  const int nblocks = B / 8;             // 8 batches per 256-thread block
  float* ws = (float*)d_ws;

  sink_kernel<<<nblocks, 256, 0, stream>>>(pred, tgt, pos, ws);
  reduce_kernel<<<1, 256, 0, stream>>>(ws, (float*)d_out, nblocks,
                                       1.005f / (float)B);
}

// Round 2
// 157.646 us; speedup vs baseline: 1.0697x; 1.0697x over previous
//
#include <hip/hip_runtime.h>
#include <math.h>

#define EXP2F(x)  __builtin_amdgcn_exp2f(x)    // v_exp_f32 = 2^x
#define LOG2FD(x) __builtin_amdgcn_logf(x)     // v_log_f32 = log2(x)
#define L2E 1.4426950408889634f

// ds_swizzle broadcast within each 32-lane group: src = J
#define SWZ(v, J)  __int_as_float(__builtin_amdgcn_ds_swizzle(__float_as_int(v), ((J) << 5)))
// ds_swizzle butterfly: src = lane ^ M (within 32-lane group)
#define SWZX(v, M) __int_as_float(__builtin_amdgcn_ds_swizzle(__float_as_int(v), ((M) << 10) | 0x1F))

#define REP32(M) \
  M(0) M(1) M(2) M(3) M(4) M(5) M(6) M(7) \
  M(8) M(9) M(10) M(11) M(12) M(13) M(14) M(15) \
  M(16) M(17) M(18) M(19) M(20) M(21) M(22) M(23) \
  M(24) M(25) M(26) M(27) M(28) M(29) M(30) M(31)

// max of v over the 32-lane group (5 swizzle + 5 max)
__device__ __forceinline__ float bmax32(float v) {
  v = fmaxf(v, SWZX(v, 1));
  v = fmaxf(v, SWZX(v, 2));
  v = fmaxf(v, SWZX(v, 4));
  v = fmaxf(v, SWZX(v, 8));
  v = fmaxf(v, SWZX(v, 16));
  return v;
}

// Kernel-trick softmin (large eps): returns L = m + log2(sum_j K_ij * 2^(H_j-m)).
// Caller multiplies by -d*eps to get the log2-scaled potential.
// Safe because C_ii = 0 => sum >= 2^(H_i - m): no catastrophic underflow while
// spread(H)*1 + maxC2*inv stays well below 126 (guaranteed for inv <= 8 here).
__device__ __forceinline__ float ksoftmin(const float Krow[32], float H) {
  const float m2 = bmax32(H);
  const float w  = EXP2F(H - m2);   // this lane's w_i, broadcast below
  float s0 = 0.f, s1 = 0.f, s2 = 0.f, s3 = 0.f;
#define KS0(J) s0 = fmaf(Krow[J], SWZ(w, J), s0);
#define KS1(J) s1 = fmaf(Krow[J], SWZ(w, J), s1);
#define KS2(J) s2 = fmaf(Krow[J], SWZ(w, J), s2);
#define KSACC(J) KS##J
  // interleave into 4 accumulators
#define KS(J) { float wj = SWZ(w, J); \
                if ((J & 3) == 0) s0 = fmaf(Krow[J], wj, s0); \
                else if ((J & 3) == 1) s1 = fmaf(Krow[J], wj, s1); \
                else if ((J & 3) == 2) s2 = fmaf(Krow[J], wj, s2); \
                else s3 = fmaf(Krow[J], wj, s3); }
  REP32(KS)
#undef KS
  const float s = (s0 + s1) + (s2 + s3);
  return m2 + LOG2FD(s);
}

// Exact per-row-stabilized softmin (small eps), log2 domain.
__device__ __forceinline__ float esoftmin(const float C2row[32], float inv, float H) {
  float arg[32];
#define EA(J) { float Hj = SWZ(H, J); arg[J] = fmaf(C2row[J], -inv, Hj); }
  REP32(EA)
#undef EA
  // 4 parallel max chains, nested fmaxf -> v_max3_f32
  float m0 = fmaxf(arg[0], arg[4]);
  float m1 = fmaxf(arg[1], arg[5]);
  float m2 = fmaxf(arg[2], arg[6]);
  float m3 = fmaxf(arg[3], arg[7]);
  m0 = fmaxf(fmaxf(m0, arg[8]),  arg[12]);
  m1 = fmaxf(fmaxf(m1, arg[9]),  arg[13]);
  m2 = fmaxf(fmaxf(m2, arg[10]), arg[14]);
  m3 = fmaxf(fmaxf(m3, arg[11]), arg[15]);
  m0 = fmaxf(fmaxf(m0, arg[16]), arg[20]);
  m1 = fmaxf(fmaxf(m1, arg[17]), arg[21]);
  m2 = fmaxf(fmaxf(m2, arg[18]), arg[22]);
  m3 = fmaxf(fmaxf(m3, arg[19]), arg[23]);
  m0 = fmaxf(fmaxf(m0, arg[24]), arg[28]);
  m1 = fmaxf(fmaxf(m1, arg[25]), arg[29]);
  m2 = fmaxf(fmaxf(m2, arg[26]), arg[30]);
  m3 = fmaxf(fmaxf(m3, arg[27]), arg[31]);
  const float m = fmaxf(fmaxf(fmaxf(m0, m1), m2), m3);
  float s0 = 0.f, s1 = 0.f, s2 = 0.f, s3 = 0.f;
#define EE(J) { float e = EXP2F(arg[J] - m); \
                if ((J & 3) == 0) s0 += e; else if ((J & 3) == 1) s1 += e; \
                else if ((J & 3) == 2) s2 += e; else s3 += e; }
  REP32(EE)
#undef EE
  const float s = (s0 + s1) + (s2 + s3);
  return m + LOG2FD(s);
}

__global__ __launch_bounds__(256) void sink_kernel(
    const float* __restrict__ pred, const float* __restrict__ tgt,
    const float* __restrict__ pos, float* __restrict__ ws) {
  const int tid  = blockIdx.x * 256 + threadIdx.x;
  const int lane = threadIdx.x & 31;   // point index i within the batch

  const float p   = pred[tid];
  const float tg  = tgt[tid];
  const float al2 = LOG2FD(p);   // log2(pred)
  const float bl2 = LOG2FD(tg);  // log2(target)

  // C2row[j] = C[i,j]*log2e = 0.5*log2e*||x_i-x_j||^2 (shared PMT layout)
  const float xi = pos[2 * lane], yi = pos[2 * lane + 1];
  float C2row[32];
#define CPOS(J) { float xj = SWZ(xi, J), yj = SWZ(yi, J); \
                  float dx = xi - xj, dy = yi - yj; \
                  C2row[J] = (0.5f * L2E) * (dx * dx + dy * dy); }
  REP32(CPOS)
#undef CPOS

  float Krow[32];
#define KB(J) Krow[J] = EXP2F(C2row[J] * ninv);
  // ---- init at eps0 = 8 (inv = 0.125) ----
  {
    const float ninv = -0.125f;
    REP32(KB)
  }
  const float nde0 = -8.f / 9.f;   // -d0*eps0
  const float LA = ksoftmin(Krow, al2);
  const float LB = ksoftmin(Krow, bl2);
  float G_ab = nde0 * LA, F_aa = nde0 * LA;
  float F_ba = nde0 * LB, G_bb = nde0 * LB;

  // ---- phase A: eps = [8, 8, 2, 0.5, 0.125], kernel-trick path ----
  const float INV_A[5] = {0.125f, 0.125f, 0.5f, 2.f, 8.f};
  const float NDE_A[5] = {-8.f/9.f, -8.f/9.f, -2.f/3.f, -1.f/3.f, -1.f/9.f};
#pragma unroll 1
  for (int k = 0; k < 5; ++k) {
    const float inv = INV_A[k], nde = NDE_A[k];
    if (k >= 2) {               // eps changed: rebuild shared kernel row
      const float ninv = -inv;
      REP32(KB)
    }
    const float Ft = nde * ksoftmin(Krow, fmaf(G_ab, inv, bl2));
    const float Gt = nde * ksoftmin(Krow, fmaf(F_ba, inv, al2));
    const float Fa = nde * ksoftmin(Krow, fmaf(F_aa, inv, al2));
    const float Gb = nde * ksoftmin(Krow, fmaf(G_bb, inv, bl2));
    F_ba = 0.5f * (F_ba + Ft); G_ab = 0.5f * (G_ab + Gt);
    F_aa = 0.5f * (F_aa + Fa); G_bb = 0.5f * (G_bb + Gb);
  }
#undef KB

  // ---- phase B: eps = [0.03125, 0.01] + final extrapolation, exact path ----
  const float INV_B[3] = {32.f, 100.f, 100.f};
  const float NDE_B[3] = {-1.f/33.f, -1.f/101.f, -1.f/101.f};
#pragma unroll 1
  for (int kb = 0; kb < 3; ++kb) {
    const float inv = INV_B[kb], nde = NDE_B[kb];
    const float Ft = nde * esoftmin(C2row, inv, fmaf(G_ab, inv, bl2));
    const float Gt = nde * esoftmin(C2row, inv, fmaf(F_ba, inv, al2));
    const float Fa = nde * esoftmin(C2row, inv, fmaf(F_aa, inv, al2));
    const float Gb = nde * esoftmin(C2row, inv, fmaf(G_bb, inv, bl2));
    if (kb < 2) {
      F_ba = 0.5f * (F_ba + Ft); G_ab = 0.5f * (G_ab + Gt);
      F_aa = 0.5f * (F_aa + Fa); G_bb = 0.5f * (G_bb + Gb);
    } else {
      F_ba = Ft; G_ab = Gt; F_aa = Fa; G_bb = Gb;
    }
  }

  // per-lane debiased unbalanced cost (RHO=1); potentials are log2-scaled
  float c = p  * (EXP2F(-F_aa) - EXP2F(-F_ba))
          + tg * (EXP2F(-G_bb) - EXP2F(-G_ab));

  // reduce over 32 lanes
  c += __shfl_xor(c, 16);
  c += __shfl_xor(c, 8);
  c += __shfl_xor(c, 4);
  c += __shfl_xor(c, 2);
  c += __shfl_xor(c, 1);

  __shared__ float bsum[8];
  if (lane == 0) bsum[threadIdx.x >> 5] = c;
  __syncthreads();
  if (threadIdx.x == 0) {
    float t = 0.f;
#pragma unroll
    for (int g = 0; g < 8; ++g) t += bsum[g];
    ws[blockIdx.x] = t;
  }
}

__global__ __launch_bounds__(256) void reduce_kernel(
    const float* __restrict__ ws, float* __restrict__ out, int n, float scale) {
  float s = 0.f;
  for (int i = threadIdx.x; i < n; i += 256) s += ws[i];
  s += __shfl_xor(s, 32);
  s += __shfl_xor(s, 16);
  s += __shfl_xor(s, 8);
  s += __shfl_xor(s, 4);
  s += __shfl_xor(s, 2);
  s += __shfl_xor(s, 1);
  __shared__ float a[4];
  if ((threadIdx.x & 63) == 0) a[threadIdx.x >> 6] = s;
  __syncthreads();
  if (threadIdx.x == 0) out[0] = ((a[0] + a[1]) + (a[2] + a[3])) * scale;
}

extern "C" void kernel_launch(void* const* d_in, const int* in_sizes, int n_in,
                              void* d_out, int out_size, void* d_ws, size_t ws_size,
                              hipStream_t stream) {
  const float* pred = (const float*)d_in[0];
  const float* tgt  = (const float*)d_in[1];
  const float* pos  = (const float*)d_in[2];
  const int B = in_sizes[0] / 32;        // 32768 batches
  const int nblocks = B / 8;             // 8 batches per 256-thread block
  float* ws = (float*)d_ws;

  sink_kernel<<<nblocks, 256, 0, stream>>>(pred, tgt, pos, ws);
  reduce_kernel<<<1, 256, 0, stream>>>(ws, (float*)d_out, nblocks,
                                       1.005f / (float)B);
}

// Round 3
// 82.421 us; speedup vs baseline: 2.0460x; 1.9127x over previous
//
#include <hip/hip_runtime.h>

#define EXP2F(x)  __builtin_amdgcn_exp2f(x)    // v_exp_f32 = 2^x
#define LOG2FD(x) __builtin_amdgcn_logf(x)     // v_log_f32 = log2(x)
#define L2E 1.4426950408889634f

typedef __attribute__((ext_vector_type(8))) short bf16x8;  // 8 bf16 = 4 VGPR
typedef __attribute__((ext_vector_type(4))) float f32x4;

#define MFMA16(A, B, C) __builtin_amdgcn_mfma_f32_16x16x32_bf16((A), (B), (C), 0, 0, 0)

union U8 { unsigned int u[4]; bf16x8 v; };

// split 8 f32 into bf16-truncated hi + bf16-truncated residual lo, packed for MFMA
__device__ __forceinline__ void split_pack(const float* w, bf16x8& hi, bf16x8& lo) {
  U8 a, b;
#pragma unroll
  for (int k = 0; k < 4; ++k) {
    float x0 = w[2*k], x1 = w[2*k+1];
    unsigned u0 = __float_as_uint(x0) & 0xFFFF0000u;
    unsigned u1 = __float_as_uint(x1) & 0xFFFF0000u;
    float r0 = x0 - __uint_as_float(u0);
    float r1 = x1 - __uint_as_float(u1);
    a.u[k] = (u0 >> 16) | u1;
    b.u[k] = ((__float_as_uint(r0) & 0xFFFF0000u) >> 16) |
             (__float_as_uint(r1) & 0xFFFF0000u);
  }
  hi = a.v; lo = b.v;
}

struct P1 {
  bf16x8 KA1, KA2, KB1, KB2;           // kernel-matrix frags (rows 0-15 / 16-31, hi/lo)
  float Gab[8], Fba[8], Faa[8], Gbb[8]; // potentials, B-layout (j = 8g+e, b = lane&15)
  float al2[8], bl2[8];                 // log2 masses, B-layout
};

__device__ __forceinline__ void buildK(const float* c2a, const float* c2b, float inv,
                                       bf16x8& KA1, bf16x8& KA2, bf16x8& KB1, bf16x8& KB2) {
  float ka[8], kb[8];
#pragma unroll
  for (int e = 0; e < 8; ++e) { ka[e] = EXP2F(-c2a[e] * inv); kb[e] = EXP2F(-c2b[e] * inv); }
  split_pack(ka, KA1, KA2);
  split_pack(kb, KB1, KB2);
}

__device__ __forceinline__ void pot_assign(float* pot, const float* Ts, int b15, int g) {
  float4 r0 = *(const float4*)&Ts[b15*36 + 8*g];
  float4 r1 = *(const float4*)&Ts[b15*36 + 8*g + 4];
  pot[0]=r0.x; pot[1]=r0.y; pot[2]=r0.z; pot[3]=r0.w;
  pot[4]=r1.x; pot[5]=r1.y; pot[6]=r1.z; pot[7]=r1.w;
}

__device__ __forceinline__ void pot_merge(float* pot, const float* Ts, int b15, int g) {
  float4 r0 = *(const float4*)&Ts[b15*36 + 8*g];
  float4 r1 = *(const float4*)&Ts[b15*36 + 8*g + 4];
  pot[0]=0.5f*(pot[0]+r0.x); pot[1]=0.5f*(pot[1]+r0.y);
  pot[2]=0.5f*(pot[2]+r0.z); pot[3]=0.5f*(pot[3]+r0.w);
  pot[4]=0.5f*(pot[4]+r1.x); pot[5]=0.5f*(pot[5]+r1.y);
  pot[6]=0.5f*(pot[6]+r1.z); pot[7]=0.5f*(pot[7]+r1.w);
}

__device__ __forceinline__ void pot_store(const float* pot, float* Ts, int b15, int g) {
  float4 r0 = {pot[0], pot[1], pot[2], pot[3]};
  float4 r1 = {pot[4], pot[5], pot[6], pot[7]};
  *(float4*)&Ts[b15*36 + 8*g]     = r0;
  *(float4*)&Ts[b15*36 + 8*g + 4] = r1;
}

// kernel-trick softmin for 16 batches: V = nde*(m + log2(K*w)), stored to slot Ts in [b][i]
__device__ __forceinline__ void ksoft_store(float* Ts, const float* H,
    bf16x8 KA1, bf16x8 KA2, bf16x8 KB1, bf16x8 KB2,
    float nde, int b15, int g) {
  float hm = fmaxf(fmaxf(fmaxf(H[0], H[1]), fmaxf(H[2], H[3])),
                   fmaxf(fmaxf(H[4], H[5]), fmaxf(H[6], H[7])));
  hm = fmaxf(hm, __shfl_xor(hm, 16));
  hm = fmaxf(hm, __shfl_xor(hm, 32));       // per-batch max (uniform over col b)
  float w[8];
#pragma unroll
  for (int e = 0; e < 8; ++e) w[e] = EXP2F(H[e] - hm);
  bf16x8 w1, w2;
  split_pack(w, w1, w2);
  f32x4 z = {0.f, 0.f, 0.f, 0.f};
  f32x4 a0 = MFMA16(KA1, w1, z);
  a0 = MFMA16(KA2, w1, a0);
  a0 = MFMA16(KA1, w2, a0);
  f32x4 a1 = MFMA16(KB1, w1, z);
  a1 = MFMA16(KB2, w1, a1);
  a1 = MFMA16(KB1, w2, a1);
  float4 v0, v1;
  v0.x = nde * (hm + LOG2FD(a0[0]));
  v0.y = nde * (hm + LOG2FD(a0[1]));
  v0.z = nde * (hm + LOG2FD(a0[2]));
  v0.w = nde * (hm + LOG2FD(a0[3]));
  v1.x = nde * (hm + LOG2FD(a1[0]));
  v1.y = nde * (hm + LOG2FD(a1[1]));
  v1.z = nde * (hm + LOG2FD(a1[2]));
  v1.w = nde * (hm + LOG2FD(a1[3]));
  *(float4*)&Ts[b15*36 + 4*g]      = v0;   // rows i = 4g+r
  *(float4*)&Ts[b15*36 + 4*g + 16] = v1;   // rows i = 16+4g+r
}

__device__ __forceinline__ void p1_iter(P1& s, float* Tw, float inv, float nde,
                                        bool mergeFirst, int b15, int g) {
  if (mergeFirst) {
    pot_merge(s.Fba, Tw + 0*576, b15, g);
    pot_merge(s.Gab, Tw + 1*576, b15, g);
    pot_merge(s.Faa, Tw + 2*576, b15, g);
    pot_merge(s.Gbb, Tw + 3*576, b15, g);
  }
  float H[8];
#pragma unroll
  for (int e = 0; e < 8; ++e) H[e] = fmaf(s.Gab[e], inv, s.bl2[e]);
  ksoft_store(Tw + 0*576, H, s.KA1, s.KA2, s.KB1, s.KB2, nde, b15, g);  // ft -> F_ba
#pragma unroll
  for (int e = 0; e < 8; ++e) H[e] = fmaf(s.Fba[e], inv, s.al2[e]);
  ksoft_store(Tw + 1*576, H, s.KA1, s.KA2, s.KB1, s.KB2, nde, b15, g);  // gt -> G_ab
#pragma unroll
  for (int e = 0; e < 8; ++e) H[e] = fmaf(s.Faa[e], inv, s.al2[e]);
  ksoft_store(Tw + 2*576, H, s.KA1, s.KA2, s.KB1, s.KB2, nde, b15, g);  // fa -> F_aa
#pragma unroll
  for (int e = 0; e < 8; ++e) H[e] = fmaf(s.Gbb[e], inv, s.bl2[e]);
  ksoft_store(Tw + 3*576, H, s.KA1, s.KA2, s.KB1, s.KB2, nde, b15, g);  // gb -> G_bb
}

// exact per-row-stabilized softmin (small eps); H shared via wave-coherent LDS
__device__ __forceinline__ float esoft(float* Hrow, const float* C2row,
                                       float myH, float inv, float nde, int i) {
  asm volatile("" ::: "memory");
  Hrow[i] = myH;
  asm volatile("" ::: "memory");
  float Hv[32];
#pragma unroll
  for (int q = 0; q < 8; ++q) {
    float4 h = *(const float4*)&Hrow[4*q];   // uniform addr -> LDS broadcast
    Hv[4*q+0] = h.x; Hv[4*q+1] = h.y; Hv[4*q+2] = h.z; Hv[4*q+3] = h.w;
  }
  float arg[32];
#pragma unroll
  for (int j = 0; j < 32; ++j) arg[j] = fmaf(C2row[j], -inv, Hv[j]);
  float m0 = fmaxf(arg[0], arg[4]);
  float m1 = fmaxf(arg[1], arg[5]);
  float m2 = fmaxf(arg[2], arg[6]);
  float m3 = fmaxf(arg[3], arg[7]);
  m0 = fmaxf(fmaxf(m0, arg[8]),  arg[12]);
  m1 = fmaxf(fmaxf(m1, arg[9]),  arg[13]);
  m2 = fmaxf(fmaxf(m2, arg[10]), arg[14]);
  m3 = fmaxf(fmaxf(m3, arg[11]), arg[15]);
  m0 = fmaxf(fmaxf(m0, arg[16]), arg[20]);
  m1 = fmaxf(fmaxf(m1, arg[17]), arg[21]);
  m2 = fmaxf(fmaxf(m2, arg[18]), arg[22]);
  m3 = fmaxf(fmaxf(m3, arg[19]), arg[23]);
  m0 = fmaxf(fmaxf(m0, arg[24]), arg[28]);
  m1 = fmaxf(fmaxf(m1, arg[25]), arg[29]);
  m2 = fmaxf(fmaxf(m2, arg[26]), arg[30]);
  m3 = fmaxf(fmaxf(m3, arg[27]), arg[31]);
  const float m = fmaxf(fmaxf(m0, m1), fmaxf(m2, m3));
  float s0 = 0.f, s1 = 0.f, s2 = 0.f, s3 = 0.f;
#pragma unroll
  for (int j = 0; j < 32; j += 4) {
    s0 += EXP2F(arg[j+0] - m);
    s1 += EXP2F(arg[j+1] - m);
    s2 += EXP2F(arg[j+2] - m);
    s3 += EXP2F(arg[j+3] - m);
  }
  return nde * (m + LOG2FD((s0 + s1) + (s2 + s3)));
}

__device__ __forceinline__ void p2_iter(float& Fba, float& Gab, float& Faa, float& Gbb,
    float la, float lb, float* Hrow, const float* C2row, int i,
    float inv, float nde, bool avg) {
  float Lft = esoft(Hrow, C2row, fmaf(Gab, inv, lb), inv, nde, i);
  float Lgt = esoft(Hrow, C2row, fmaf(Fba, inv, la), inv, nde, i);
  float Lfa = esoft(Hrow, C2row, fmaf(Faa, inv, la), inv, nde, i);
  float Lgb = esoft(Hrow, C2row, fmaf(Gbb, inv, lb), inv, nde, i);
  if (avg) {
    Fba = 0.5f*(Fba + Lft); Gab = 0.5f*(Gab + Lgt);
    Faa = 0.5f*(Faa + Lfa); Gbb = 0.5f*(Gbb + Lgb);
  } else {
    Fba = Lft; Gab = Lgt; Faa = Lfa; Gbb = Lgb;
  }
}

__global__ __launch_bounds__(256) void sink_kernel(
    const float* __restrict__ pred, const float* __restrict__ tgt,
    const float* __restrict__ pos, float* __restrict__ ws) {
  __shared__ __align__(16) float sC2[32][36];     // shared cost*log2e, padded
  __shared__ __align__(16) float sT[4][4][576];   // [wave][slot][b*36+idx]
  __shared__ __align__(16) float sM[4][2][576];   // [wave][a/b][b*36+j] log2 masses
  __shared__ __align__(16) float sH[4][2][32];    // [wave][half][j]
  __shared__ float sB[4];

  const int lid = threadIdx.x & 63;
  const int wid = threadIdx.x >> 6;
  const int b15 = lid & 15;
  const int g   = lid >> 4;
  const int bbase = blockIdx.x * 64 + wid * 16;   // this wave's 16 batches

  // ---------------- phase 1: eps >= 0.125, MFMA kernel-trick ----------------
  P1 s;
  {
    const float* pr = &pred[(bbase + b15) * 32 + 8 * g];
    const float* tr = &tgt [(bbase + b15) * 32 + 8 * g];
    float4 p0 = *(const float4*)&pr[0];
    float4 p1 = *(const float4*)&pr[4];
    float4 t0 = *(const float4*)&tr[0];
    float4 t1 = *(const float4*)&tr[4];
    s.al2[0]=LOG2FD(p0.x); s.al2[1]=LOG2FD(p0.y); s.al2[2]=LOG2FD(p0.z); s.al2[3]=LOG2FD(p0.w);
    s.al2[4]=LOG2FD(p1.x); s.al2[5]=LOG2FD(p1.y); s.al2[6]=LOG2FD(p1.z); s.al2[7]=LOG2FD(p1.w);
    s.bl2[0]=LOG2FD(t0.x); s.bl2[1]=LOG2FD(t0.y); s.bl2[2]=LOG2FD(t0.z); s.bl2[3]=LOG2FD(t0.w);
    s.bl2[4]=LOG2FD(t1.x); s.bl2[5]=LOG2FD(t1.y); s.bl2[6]=LOG2FD(t1.z); s.bl2[7]=LOG2FD(t1.w);
  }
  float c2a[8], c2b[8];   // C*log2e rows b15 and b15+16, cols j=8g+e
  {
    float2 pm0 = ((const float2*)pos)[b15];
    float2 pm1 = ((const float2*)pos)[b15 + 16];
#pragma unroll
    for (int e = 0; e < 8; ++e) {
      float2 pj = ((const float2*)pos)[8*g + e];
      float dx0 = pm0.x - pj.x, dy0 = pm0.y - pj.y;
      float dx1 = pm1.x - pj.x, dy1 = pm1.y - pj.y;
      c2a[e] = (0.5f*L2E)*(dx0*dx0 + dy0*dy0);
      c2b[e] = (0.5f*L2E)*(dx1*dx1 + dy1*dy1);
    }
  }
  if (wid == 0) {
    float4 a0 = {c2a[0], c2a[1], c2a[2], c2a[3]};
    float4 a1 = {c2a[4], c2a[5], c2a[6], c2a[7]};
    float4 b0 = {c2b[0], c2b[1], c2b[2], c2b[3]};
    float4 b1 = {c2b[4], c2b[5], c2b[6], c2b[7]};
    *(float4*)&sC2[b15][8*g]        = a0;
    *(float4*)&sC2[b15][8*g + 4]    = a1;
    *(float4*)&sC2[b15+16][8*g]     = b0;
    *(float4*)&sC2[b15+16][8*g + 4] = b1;
  }
  float* Tw = &sT[wid][0][0];
  float* Mw = &sM[wid][0][0];

  buildK(c2a, c2b, 0.125f, s.KA1, s.KA2, s.KB1, s.KB2);
  // init at eps0=8: two unique softmins
  ksoft_store(Tw + 1*576, s.al2, s.KA1, s.KA2, s.KB1, s.KB2, -8.f/9.f, b15, g);
  ksoft_store(Tw + 0*576, s.bl2, s.KA1, s.KA2, s.KB1, s.KB2, -8.f/9.f, b15, g);
  pot_assign(s.Gab, Tw + 1*576, b15, g);
  pot_assign(s.Fba, Tw + 0*576, b15, g);
#pragma unroll
  for (int e = 0; e < 8; ++e) { s.Faa[e] = s.Gab[e]; s.Gbb[e] = s.Fba[e]; }

  p1_iter(s, Tw, 0.125f, -8.f/9.f, false, b15, g);                               // eps=8
  p1_iter(s, Tw, 0.125f, -8.f/9.f, true,  b15, g);                               // eps=8
  buildK(c2a, c2b, 0.5f, s.KA1, s.KA2, s.KB1, s.KB2);
  p1_iter(s, Tw, 0.5f, -2.f/3.f, true, b15, g);                                  // eps=2
  buildK(c2a, c2b, 2.f, s.KA1, s.KA2, s.KB1, s.KB2);
  p1_iter(s, Tw, 2.f, -1.f/3.f, true, b15, g);                                   // eps=0.5
  buildK(c2a, c2b, 8.f, s.KA1, s.KA2, s.KB1, s.KB2);
  p1_iter(s, Tw, 8.f, -1.f/9.f, true, b15, g);                                   // eps=0.125

  pot_merge(s.Fba, Tw + 0*576, b15, g);
  pot_merge(s.Gab, Tw + 1*576, b15, g);
  pot_merge(s.Faa, Tw + 2*576, b15, g);
  pot_merge(s.Gbb, Tw + 3*576, b15, g);
  pot_store(s.Fba, Tw + 0*576, b15, g);
  pot_store(s.Gab, Tw + 1*576, b15, g);
  pot_store(s.Faa, Tw + 2*576, b15, g);
  pot_store(s.Gbb, Tw + 3*576, b15, g);
  pot_store(s.al2, Mw,        b15, g);
  pot_store(s.bl2, Mw + 576,  b15, g);
  __syncthreads();   // publish sC2 (wave0 -> all); per-wave data is wave-coherent

  // ---------------- phase 2: eps <= 0.03125, exact path, 2 batches/wave ----------------
  const int i = lid & 31, half = lid >> 5;
  float C2row[32];
#pragma unroll
  for (int q = 0; q < 8; ++q) {
    float4 v = *(const float4*)&sC2[i][4*q];
    C2row[4*q+0] = v.x; C2row[4*q+1] = v.y; C2row[4*q+2] = v.z; C2row[4*q+3] = v.w;
  }
  float* Hrow = &sH[wid][half][0];
  float cacc = 0.f;
#pragma unroll 1
  for (int p = 0; p < 8; ++p) {
    const int b  = 2*p + half;
    const int gb = bbase + b;
    float Fba = Tw[0*576 + b*36 + i];
    float Gab = Tw[1*576 + b*36 + i];
    float Faa = Tw[2*576 + b*36 + i];
    float Gbb = Tw[3*576 + b*36 + i];
    float la  = Mw[b*36 + i];
    float lb  = Mw[576 + b*36 + i];
    float pv  = pred[gb*32 + i];
    float tv  = tgt [gb*32 + i];
    p2_iter(Fba, Gab, Faa, Gbb, la, lb, Hrow, C2row, i, 32.f,  -1.f/33.f,  true);
    p2_iter(Fba, Gab, Faa, Gbb, la, lb, Hrow, C2row, i, 100.f, -1.f/101.f, true);
    p2_iter(Fba, Gab, Faa, Gbb, la, lb, Hrow, C2row, i, 100.f, -1.f/101.f, false);
    cacc += pv * (EXP2F(-Faa) - EXP2F(-Fba)) + tv * (EXP2F(-Gbb) - EXP2F(-Gab));
  }
  cacc += __shfl_xor(cacc, 32);
  cacc += __shfl_xor(cacc, 16);
  cacc += __shfl_xor(cacc, 8);
  cacc += __shfl_xor(cacc, 4);
  cacc += __shfl_xor(cacc, 2);
  cacc += __shfl_xor(cacc, 1);
  if (lid == 0) sB[wid] = cacc;
  __syncthreads();
  if (threadIdx.x == 0) ws[blockIdx.x] = (sB[0] + sB[1]) + (sB[2] + sB[3]);
}

__global__ __launch_bounds__(256) void reduce_kernel(
    const float* __restrict__ ws, float* __restrict__ out, int n, float scale) {
  float s = 0.f;
  for (int i = threadIdx.x; i < n; i += 256) s += ws[i];
  s += __shfl_xor(s, 32);
  s += __shfl_xor(s, 16);
  s += __shfl_xor(s, 8);
  s += __shfl_xor(s, 4);
  s += __shfl_xor(s, 2);
  s += __shfl_xor(s, 1);
  __shared__ float a[4];
  if ((threadIdx.x & 63) == 0) a[threadIdx.x >> 6] = s;
  __syncthreads();
  if (threadIdx.x == 0) out[0] = ((a[0] + a[1]) + (a[2] + a[3])) * scale;
}

extern "C" void kernel_launch(void* const* d_in, const int* in_sizes, int n_in,
                              void* d_out, int out_size, void* d_ws, size_t ws_size,
                              hipStream_t stream) {
  const float* pred = (const float*)d_in[0];
  const float* tgt  = (const float*)d_in[1];
  const float* pos  = (const float*)d_in[2];
  const int B = in_sizes[0] / 32;        // 32768 batches
  const int nblocks = B / 64;            // 64 batches per 256-thread block = 512
  float* ws = (float*)d_ws;

  sink_kernel<<<nblocks, 256, 0, stream>>>(pred, tgt, pos, ws);
  reduce_kernel<<<1, 256, 0, stream>>>(ws, (float*)d_out, nblocks,
                                       1.005f / (float)B);
}

// Round 4
// 56.258 us; speedup vs baseline: 2.9975x; 1.4651x over previous
//
#include <hip/hip_runtime.h>

#define EXP2F(x)  __builtin_amdgcn_exp2f(x)    // v_exp_f32 = 2^x
#define LOG2FD(x) __builtin_amdgcn_logf(x)     // v_log_f32 = log2(x)
#define L2E 1.4426950408889634f

typedef __attribute__((ext_vector_type(8))) short bf16x8;  // 8 bf16 = 4 VGPR
typedef __attribute__((ext_vector_type(4))) float f32x4;

#define MFMA16(A, B, C) __builtin_amdgcn_mfma_f32_16x16x32_bf16((A), (B), (C), 0, 0, 0)

// ds_swizzle butterfly: src = lane ^ M (within 32-lane group)
#define SWZX(v, M) __int_as_float(__builtin_amdgcn_ds_swizzle(__float_as_int(v), ((M) << 10) | 0x1F))

union U8 { unsigned int u[4]; bf16x8 v; };

// split 8 f32 into bf16-truncated hi + bf16-truncated residual lo, packed for MFMA
__device__ __forceinline__ void split_pack(const float* w, bf16x8& hi, bf16x8& lo) {
  U8 a, b;
#pragma unroll
  for (int k = 0; k < 4; ++k) {
    float x0 = w[2*k], x1 = w[2*k+1];
    unsigned u0 = __float_as_uint(x0) & 0xFFFF0000u;
    unsigned u1 = __float_as_uint(x1) & 0xFFFF0000u;
    float r0 = x0 - __uint_as_float(u0);
    float r1 = x1 - __uint_as_float(u1);
    a.u[k] = (u0 >> 16) | u1;
    b.u[k] = ((__float_as_uint(r0) & 0xFFFF0000u) >> 16) |
             (__float_as_uint(r1) & 0xFFFF0000u);
  }
  hi = a.v; lo = b.v;
}

struct P1 {
  bf16x8 KA1, KA2, KB1, KB2;            // kernel-matrix frags (rows 0-15 / 16-31, hi/lo)
  float Gab[8], Fba[8], Faa[8], Gbb[8]; // potentials, B-layout (j = 8g+e, b = lane&15)
  float al2[8], bl2[8];                 // log2 masses, B-layout
};

__device__ __forceinline__ void buildK(const float* c2a, const float* c2b, float inv,
                                       bf16x8& KA1, bf16x8& KA2, bf16x8& KB1, bf16x8& KB2) {
  float ka[8], kb[8];
#pragma unroll
  for (int e = 0; e < 8; ++e) { ka[e] = EXP2F(-c2a[e] * inv); kb[e] = EXP2F(-c2b[e] * inv); }
  split_pack(ka, KA1, KA2);
  split_pack(kb, KB1, KB2);
}

__device__ __forceinline__ void pot_assign(float* pot, const float* Ts, int b15, int g) {
  float4 r0 = *(const float4*)&Ts[b15*36 + 8*g];
  float4 r1 = *(const float4*)&Ts[b15*36 + 8*g + 4];
  pot[0]=r0.x; pot[1]=r0.y; pot[2]=r0.z; pot[3]=r0.w;
  pot[4]=r1.x; pot[5]=r1.y; pot[6]=r1.z; pot[7]=r1.w;
}

__device__ __forceinline__ void pot_merge(float* pot, const float* Ts, int b15, int g) {
  float4 r0 = *(const float4*)&Ts[b15*36 + 8*g];
  float4 r1 = *(const float4*)&Ts[b15*36 + 8*g + 4];
  pot[0]=0.5f*(pot[0]+r0.x); pot[1]=0.5f*(pot[1]+r0.y);
  pot[2]=0.5f*(pot[2]+r0.z); pot[3]=0.5f*(pot[3]+r0.w);
  pot[4]=0.5f*(pot[4]+r1.x); pot[5]=0.5f*(pot[5]+r1.y);
  pot[6]=0.5f*(pot[6]+r1.z); pot[7]=0.5f*(pot[7]+r1.w);
}

__device__ __forceinline__ void pot_store(const float* pot, float* Ts, int b15, int g) {
  float4 r0 = {pot[0], pot[1], pot[2], pot[3]};
  float4 r1 = {pot[4], pot[5], pot[6], pot[7]};
  *(float4*)&Ts[b15*36 + 8*g]     = r0;
  *(float4*)&Ts[b15*36 + 8*g + 4] = r1;
}

// kernel-trick softmin for 16 batches: V = nde*(m + log2(K*w)), stored to slot Ts in [b][i]
__device__ __forceinline__ void ksoft_store(float* Ts, const float* H,
    bf16x8 KA1, bf16x8 KA2, bf16x8 KB1, bf16x8 KB2,
    float nde, int b15, int g) {
  float hm = fmaxf(fmaxf(fmaxf(H[0], H[1]), fmaxf(H[2], H[3])),
                   fmaxf(fmaxf(H[4], H[5]), fmaxf(H[6], H[7])));
  hm = fmaxf(hm, __shfl_xor(hm, 16));
  hm = fmaxf(hm, __shfl_xor(hm, 32));       // per-batch max (uniform over col b)
  float w[8];
#pragma unroll
  for (int e = 0; e < 8; ++e) w[e] = EXP2F(H[e] - hm);
  bf16x8 w1, w2;
  split_pack(w, w1, w2);
  f32x4 z = {0.f, 0.f, 0.f, 0.f};
  f32x4 a0 = MFMA16(KA1, w1, z);
  a0 = MFMA16(KA2, w1, a0);
  a0 = MFMA16(KA1, w2, a0);
  f32x4 a1 = MFMA16(KB1, w1, z);
  a1 = MFMA16(KB2, w1, a1);
  a1 = MFMA16(KB1, w2, a1);
  float4 v0, v1;
  v0.x = nde * (hm + LOG2FD(a0[0]));
  v0.y = nde * (hm + LOG2FD(a0[1]));
  v0.z = nde * (hm + LOG2FD(a0[2]));
  v0.w = nde * (hm + LOG2FD(a0[3]));
  v1.x = nde * (hm + LOG2FD(a1[0]));
  v1.y = nde * (hm + LOG2FD(a1[1]));
  v1.z = nde * (hm + LOG2FD(a1[2]));
  v1.w = nde * (hm + LOG2FD(a1[3]));
  *(float4*)&Ts[b15*36 + 4*g]      = v0;   // rows i = 4g+r
  *(float4*)&Ts[b15*36 + 4*g + 16] = v1;   // rows i = 16+4g+r
}

__device__ __forceinline__ void p1_iter(P1& s, float* Tw, float inv, float nde,
                                        bool mergeFirst, int b15, int g) {
  if (mergeFirst) {
    pot_merge(s.Fba, Tw + 0*576, b15, g);
    pot_merge(s.Gab, Tw + 1*576, b15, g);
    pot_merge(s.Faa, Tw + 2*576, b15, g);
    pot_merge(s.Gbb, Tw + 3*576, b15, g);
  }
  float H[8];
#pragma unroll
  for (int e = 0; e < 8; ++e) H[e] = fmaf(s.Gab[e], inv, s.bl2[e]);
  ksoft_store(Tw + 0*576, H, s.KA1, s.KA2, s.KB1, s.KB2, nde, b15, g);  // ft -> F_ba
#pragma unroll
  for (int e = 0; e < 8; ++e) H[e] = fmaf(s.Fba[e], inv, s.al2[e]);
  ksoft_store(Tw + 1*576, H, s.KA1, s.KA2, s.KB1, s.KB2, nde, b15, g);  // gt -> G_ab
#pragma unroll
  for (int e = 0; e < 8; ++e) H[e] = fmaf(s.Faa[e], inv, s.al2[e]);
  ksoft_store(Tw + 2*576, H, s.KA1, s.KA2, s.KB1, s.KB2, nde, b15, g);  // fa -> F_aa
#pragma unroll
  for (int e = 0; e < 8; ++e) H[e] = fmaf(s.Gbb[e], inv, s.bl2[e]);
  ksoft_store(Tw + 3*576, H, s.KA1, s.KA2, s.KB1, s.KB2, nde, b15, g);  // gb -> G_bb
}

// exact max over each 32-lane half: 4 VALU DPP row_ror maxes + 1 swizzle (xor16)
__device__ __forceinline__ float rowmax32(float v) {
#define DPPMAX(C) v = fmaxf(v, __int_as_float(__builtin_amdgcn_update_dpp( \
    __float_as_int(v), __float_as_int(v), (C), 0xF, 0xF, false)));
  DPPMAX(0x121)  // row_ror:1
  DPPMAX(0x122)  // row_ror:2
  DPPMAX(0x124)  // row_ror:4
  DPPMAX(0x128)  // row_ror:8
#undef DPPMAX
  v = fmaxf(v, SWZX(v, 16));
  return v;
}

// Fast softmin: raw_i = log2 sum_j 2^(H_j - C2_ij*inv) = mH + log2(sum_j K_ij*w_j),
// w_j = 2^(H_j-mH) shared via LDS (1 exp/lane). If S < 2^-90 the row's scale is
// too far below mH (possible flush of significant terms) -> exact per-lane fallback.
__device__ __forceinline__ float fastsm(float* Hb, float* Wb, const float* K,
    float H, float inv, float nde, int i,
    float xi, float yi, const float2* pos2) {
  const float mH = rowmax32(H);
  const float w  = EXP2F(H - mH);
  Hb[i] = H;
  Wb[i] = w;
  asm volatile("" ::: "memory");
  float s0 = 0.f, s1 = 0.f, s2 = 0.f, s3 = 0.f;
#pragma unroll
  for (int t = 0; t < 8; ++t) {
    float4 wv = *(const float4*)&Wb[4*t];   // uniform addr per half -> broadcast
    s0 = fmaf(K[4*t+0], wv.x, s0);
    s1 = fmaf(K[4*t+1], wv.y, s1);
    s2 = fmaf(K[4*t+2], wv.z, s2);
    s3 = fmaf(K[4*t+3], wv.w, s3);
  }
  const float S = (s0 + s1) + (s2 + s3);
  float raw;
  if (__builtin_expect(S < 8.0e-28f, 0)) {      // 2^-90: exact two-pass fallback
    float m = -3.4e38f;
#pragma unroll
    for (int j = 0; j < 32; ++j) {
      float2 pj = pos2[j];
      float dx = xi - pj.x, dy = yi - pj.y;
      float c2 = (0.5f*L2E)*(dx*dx + dy*dy);
      m = fmaxf(m, fmaf(c2, -inv, Hb[j]));
    }
    float s = 0.f;
#pragma unroll
    for (int j = 0; j < 32; ++j) {
      float2 pj = pos2[j];
      float dx = xi - pj.x, dy = yi - pj.y;
      float c2 = (0.5f*L2E)*(dx*dx + dy*dy);
      s += EXP2F(fmaf(c2, -inv, Hb[j]) - m);
    }
    raw = m + LOG2FD(s);
  } else {
    raw = mH + LOG2FD(S);
  }
  return nde * raw;
}

__device__ __forceinline__ void p2x(float& Fba, float& Gab, float& Faa, float& Gbb,
    float la, float lb, float* Hb, float* Wb, const float* K,
    float inv, float nde, int i, float xi, float yi, const float2* pos2, bool avg) {
  float Lft = fastsm(Hb, Wb, K, fmaf(Gab, inv, lb), inv, nde, i, xi, yi, pos2);
  float Lgt = fastsm(Hb, Wb, K, fmaf(Fba, inv, la), inv, nde, i, xi, yi, pos2);
  float Lfa = fastsm(Hb, Wb, K, fmaf(Faa, inv, la), inv, nde, i, xi, yi, pos2);
  float Lgb = fastsm(Hb, Wb, K, fmaf(Gbb, inv, lb), inv, nde, i, xi, yi, pos2);
  if (avg) {
    Fba = 0.5f*(Fba + Lft); Gab = 0.5f*(Gab + Lgt);
    Faa = 0.5f*(Faa + Lfa); Gbb = 0.5f*(Gbb + Lgb);
  } else {
    Fba = Lft; Gab = Lgt; Faa = Lfa; Gbb = Lgb;
  }
}

__global__ __launch_bounds__(64, 2) void sink_kernel(
    const float* __restrict__ pred, const float* __restrict__ tgt,
    const float* __restrict__ pos, float* __restrict__ ws) {
  __shared__ __align__(16) float sT[4][576];   // [slot][b*36+i] potentials (1 wave/block)
  __shared__ __align__(16) float sH[2][36];    // [half][j] current H row
  __shared__ __align__(16) float sW[2][36];    // [half][j] current w row

  const int lid = threadIdx.x;          // 0..63
  const int b15 = lid & 15;
  const int g   = lid >> 4;
  const int bbase = blockIdx.x * 16;    // this wave's 16 batches
  const float2* pos2 = (const float2*)pos;

  // ---------------- phase 1: eps >= 0.125, MFMA kernel-trick ----------------
  P1 s;
  {
    const float* pr = &pred[(bbase + b15) * 32 + 8 * g];
    const float* tr = &tgt [(bbase + b15) * 32 + 8 * g];
    float4 p0 = *(const float4*)&pr[0];
    float4 p1 = *(const float4*)&pr[4];
    float4 t0 = *(const float4*)&tr[0];
    float4 t1 = *(const float4*)&tr[4];
    s.al2[0]=LOG2FD(p0.x); s.al2[1]=LOG2FD(p0.y); s.al2[2]=LOG2FD(p0.z); s.al2[3]=LOG2FD(p0.w);
    s.al2[4]=LOG2FD(p1.x); s.al2[5]=LOG2FD(p1.y); s.al2[6]=LOG2FD(p1.z); s.al2[7]=LOG2FD(p1.w);
    s.bl2[0]=LOG2FD(t0.x); s.bl2[1]=LOG2FD(t0.y); s.bl2[2]=LOG2FD(t0.z); s.bl2[3]=LOG2FD(t0.w);
    s.bl2[4]=LOG2FD(t1.x); s.bl2[5]=LOG2FD(t1.y); s.bl2[6]=LOG2FD(t1.z); s.bl2[7]=LOG2FD(t1.w);
  }
  float c2a[8], c2b[8];   // C*log2e rows b15 and b15+16, cols j=8g+e
  {
    float2 pm0 = pos2[b15];
    float2 pm1 = pos2[b15 + 16];
#pragma unroll
    for (int e = 0; e < 8; ++e) {
      float2 pj = pos2[8*g + e];
      float dx0 = pm0.x - pj.x, dy0 = pm0.y - pj.y;
      float dx1 = pm1.x - pj.x, dy1 = pm1.y - pj.y;
      c2a[e] = (0.5f*L2E)*(dx0*dx0 + dy0*dy0);
      c2b[e] = (0.5f*L2E)*(dx1*dx1 + dy1*dy1);
    }
  }
  float* Tw = &sT[0][0];

  buildK(c2a, c2b, 0.125f, s.KA1, s.KA2, s.KB1, s.KB2);
  // init at eps0=8: two unique softmins
  ksoft_store(Tw + 1*576, s.al2, s.KA1, s.KA2, s.KB1, s.KB2, -8.f/9.f, b15, g);
  ksoft_store(Tw + 0*576, s.bl2, s.KA1, s.KA2, s.KB1, s.KB2, -8.f/9.f, b15, g);
  pot_assign(s.Gab, Tw + 1*576, b15, g);
  pot_assign(s.Fba, Tw + 0*576, b15, g);
#pragma unroll
  for (int e = 0; e < 8; ++e) { s.Faa[e] = s.Gab[e]; s.Gbb[e] = s.Fba[e]; }

  p1_iter(s, Tw, 0.125f, -8.f/9.f, false, b15, g);   // eps=8
  p1_iter(s, Tw, 0.125f, -8.f/9.f, true,  b15, g);   // eps=8
  buildK(c2a, c2b, 0.5f, s.KA1, s.KA2, s.KB1, s.KB2);
  p1_iter(s, Tw, 0.5f, -2.f/3.f, true, b15, g);      // eps=2
  buildK(c2a, c2b, 2.f, s.KA1, s.KA2, s.KB1, s.KB2);
  p1_iter(s, Tw, 2.f, -1.f/3.f, true, b15, g);       // eps=0.5
  buildK(c2a, c2b, 8.f, s.KA1, s.KA2, s.KB1, s.KB2);
  p1_iter(s, Tw, 8.f, -1.f/9.f, true, b15, g);       // eps=0.125

  pot_merge(s.Fba, Tw + 0*576, b15, g);
  pot_merge(s.Gab, Tw + 1*576, b15, g);
  pot_merge(s.Faa, Tw + 2*576, b15, g);
  pot_merge(s.Gbb, Tw + 3*576, b15, g);
  pot_store(s.Fba, Tw + 0*576, b15, g);
  pot_store(s.Gab, Tw + 1*576, b15, g);
  pot_store(s.Faa, Tw + 2*576, b15, g);
  pot_store(s.Gbb, Tw + 3*576, b15, g);
  asm volatile("" ::: "memory");   // same-wave LDS ordering; no barrier needed

  // ---------------- phase 2: eps <= 0.03125, shared-w softmin ----------------
  const int i = lid & 31, half = lid >> 5;
  const float xi = pos[2*i], yi = pos[2*i + 1];

  // per-thread kernel rows (f32, amortized over 8 batches x 12 softmins)
  float K32a[32], K100a[32];
#pragma unroll
  for (int j = 0; j < 32; ++j) {
    float2 pj = pos2[j];
    float dx = xi - pj.x, dy = yi - pj.y;
    float c2 = (0.5f*L2E)*(dx*dx + dy*dy);
    K32a[j]  = EXP2F(c2 * -32.f);
    K100a[j] = EXP2F(c2 * -100.f);
  }

  float* Hb = &sH[half][0];
  float* Wb = &sW[half][0];
  float cacc = 0.f;
#pragma unroll 1
  for (int p = 0; p < 8; ++p) {
    const int b  = 2*p + half;
    const int gb = bbase + b;
    const float pv = pred[gb*32 + i];
    const float tv = tgt [gb*32 + i];
    const float la = LOG2FD(pv);
    const float lb = LOG2FD(tv);
    float Fba = Tw[0*576 + b*36 + i];
    float Gab = Tw[1*576 + b*36 + i];
    float Faa = Tw[2*576 + b*36 + i];
    float Gbb = Tw[3*576 + b*36 + i];
    p2x(Fba, Gab, Faa, Gbb, la, lb, Hb, Wb, K32a,  32.f,  -1.f/33.f,  i, xi, yi, pos2, true);
    p2x(Fba, Gab, Faa, Gbb, la, lb, Hb, Wb, K100a, 100.f, -1.f/101.f, i, xi, yi, pos2, true);
    p2x(Fba, Gab, Faa, Gbb, la, lb, Hb, Wb, K100a, 100.f, -1.f/101.f, i, xi, yi, pos2, false);
    cacc += pv * (EXP2F(-Faa) - EXP2F(-Fba)) + tv * (EXP2F(-Gbb) - EXP2F(-Gab));
  }

  cacc += __shfl_xor(cacc, 32);
  cacc += __shfl_xor(cacc, 16);
  cacc += __shfl_xor(cacc, 8);
  cacc += __shfl_xor(cacc, 4);
  cacc += __shfl_xor(cacc, 2);
  cacc += __shfl_xor(cacc, 1);
  if (lid == 0) ws[blockIdx.x] = cacc;
}

__global__ __launch_bounds__(256) void reduce_kernel(
    const float* __restrict__ ws, float* __restrict__ out, int n, float scale) {
  float s = 0.f;
  for (int i = threadIdx.x; i < n; i += 256) s += ws[i];
  s += __shfl_xor(s, 32);
  s += __shfl_xor(s, 16);
  s += __shfl_xor(s, 8);
  s += __shfl_xor(s, 4);
  s += __shfl_xor(s, 2);
  s += __shfl_xor(s, 1);
  __shared__ float a[4];
  if ((threadIdx.x & 63) == 0) a[threadIdx.x >> 6] = s;
  __syncthreads();
  if (threadIdx.x == 0) out[0] = ((a[0] + a[1]) + (a[2] + a[3])) * scale;
}

extern "C" void kernel_launch(void* const* d_in, const int* in_sizes, int n_in,
                              void* d_out, int out_size, void* d_ws, size_t ws_size,
                              hipStream_t stream) {
  const float* pred = (const float*)d_in[0];
  const float* tgt  = (const float*)d_in[1];
  const float* pos  = (const float*)d_in[2];
  const int B = in_sizes[0] / 32;        // 32768 batches
  const int nblocks = B / 16;            // 16 batches per 64-thread wave = 2048
  float* ws = (float*)d_ws;

  sink_kernel<<<nblocks, 64, 0, stream>>>(pred, tgt, pos, ws);
  reduce_kernel<<<1, 256, 0, stream>>>(ws, (float*)d_out, nblocks,
                                       1.005f / (float)B);
}

// Round 5
// 30.331 us; speedup vs baseline: 5.5598x; 1.8548x over previous
//
#include <hip/hip_runtime.h>

#define EXP2F(x)  __builtin_amdgcn_exp2f(x)    // v_exp_f32 = 2^x
#define LOG2FD(x) __builtin_amdgcn_logf(x)     // v_log_f32 = log2(x)
#define L2E 1.4426950408889634f
#define T1F 1.2621774e-29f                     // 2^-96: min trustworthy MFMA sum

typedef __attribute__((ext_vector_type(8))) short bf16x8;  // 8 bf16 = 4 VGPR
typedef __attribute__((ext_vector_type(4))) float f32x4;

#define MFMA16(A, B, C) __builtin_amdgcn_mfma_f32_16x16x32_bf16((A), (B), (C), 0, 0, 0)

union U8 { unsigned int u[4]; bf16x8 v; };

// split 8 f32 into bf16-truncated hi + bf16-truncated residual lo, packed for MFMA
__device__ __forceinline__ void split_pack(const float* w, bf16x8& hi, bf16x8& lo) {
  U8 a, b;
#pragma unroll
  for (int k = 0; k < 4; ++k) {
    float x0 = w[2*k], x1 = w[2*k+1];
    unsigned u0 = __float_as_uint(x0) & 0xFFFF0000u;
    unsigned u1 = __float_as_uint(x1) & 0xFFFF0000u;
    float r0 = x0 - __uint_as_float(u0);
    float r1 = x1 - __uint_as_float(u1);
    a.u[k] = (u0 >> 16) | u1;
    b.u[k] = ((__float_as_uint(r0) & 0xFFFF0000u) >> 16) |
             (__float_as_uint(r1) & 0xFFFF0000u);
  }
  hi = a.v; lo = b.v;
}

struct P1 {
  bf16x8 KA1, KA2, KB1, KB2;            // kernel-matrix frags (rows 0-15 / 16-31, hi/lo)
  float Gab[8], Fba[8], Faa[8], Gbb[8]; // potentials, B-layout (lane b15 = batch, j = 8g+e)
  float al2[8], bl2[8];                 // log2 masses, B-layout
};

__device__ __forceinline__ void buildK(const float* c2a, const float* c2b, float inv,
                                       bf16x8& KA1, bf16x8& KA2, bf16x8& KB1, bf16x8& KB2) {
  float ka[8], kb[8];
#pragma unroll
  for (int e = 0; e < 8; ++e) { ka[e] = EXP2F(-c2a[e] * inv); kb[e] = EXP2F(-c2b[e] * inv); }
  split_pack(ka, KA1, KA2);
  split_pack(kb, KB1, KB2);
}

__device__ __forceinline__ void pot_assign(float* pot, const float* Ts, int b15, int g) {
  float4 r0 = *(const float4*)&Ts[b15*36 + 8*g];
  float4 r1 = *(const float4*)&Ts[b15*36 + 8*g + 4];
  pot[0]=r0.x; pot[1]=r0.y; pot[2]=r0.z; pot[3]=r0.w;
  pot[4]=r1.x; pot[5]=r1.y; pot[6]=r1.z; pot[7]=r1.w;
}

__device__ __forceinline__ void pot_merge(float* pot, const float* Ts, int b15, int g) {
  float4 r0 = *(const float4*)&Ts[b15*36 + 8*g];
  float4 r1 = *(const float4*)&Ts[b15*36 + 8*g + 4];
  pot[0]=0.5f*(pot[0]+r0.x); pot[1]=0.5f*(pot[1]+r0.y);
  pot[2]=0.5f*(pot[2]+r0.z); pot[3]=0.5f*(pot[3]+r0.w);
  pot[4]=0.5f*(pot[4]+r1.x); pot[5]=0.5f*(pot[5]+r1.y);
  pot[6]=0.5f*(pot[6]+r1.z); pot[7]=0.5f*(pot[7]+r1.w);
}

// rare exact per-row logsumexp: arg_j = H_j - c2(i,j)*inv, H from LDS row
__device__ __noinline__ float exact_lse(const float2* pos2, const float* HB,
                                        int i, float inv) {
  float2 pi = pos2[i];
  float m = -3.4e38f;
#pragma unroll 1
  for (int j = 0; j < 32; ++j) {
    float2 pj = pos2[j];
    float dx = pi.x - pj.x, dy = pi.y - pj.y;
    float arg = fmaf((0.5f*L2E)*(dx*dx + dy*dy), -inv, HB[j]);
    m = fmaxf(m, arg);
  }
  float s = 0.f;
#pragma unroll 1
  for (int j = 0; j < 32; ++j) {
    float2 pj = pos2[j];
    float dx = pi.x - pj.x, dy = pi.y - pj.y;
    float arg = fmaf((0.5f*L2E)*(dx*dx + dy*dy), -inv, HB[j]);
    s += EXP2F(arg - m);
  }
  return m + LOG2FD(s);
}

// MFMA softmin for 16 batches. CHECKED adds the S2 rescue scale (+96) and the
// exact fallback for rows beyond 192 log2-units below the batch max.
template<bool CHECKED>
__device__ __forceinline__ void ksoft(float* Ts, float* Hdump, const float* H,
    bf16x8 KA1, bf16x8 KA2, bf16x8 KB1, bf16x8 KB2,
    float nde, float inv, int b15, int g, const float2* pos2) {
  float hm = fmaxf(fmaxf(fmaxf(H[0], H[1]), fmaxf(H[2], H[3])),
                   fmaxf(fmaxf(H[4], H[5]), fmaxf(H[6], H[7])));
  hm = fmaxf(hm, __shfl_xor(hm, 16));
  hm = fmaxf(hm, __shfl_xor(hm, 32));       // per-batch max over all 32 j
  float d[8], w[8];
#pragma unroll
  for (int e = 0; e < 8; ++e) { d[e] = H[e] - hm; w[e] = EXP2F(d[e]); }
  bf16x8 w1, w2;
  split_pack(w, w1, w2);
  f32x4 z = {0.f, 0.f, 0.f, 0.f};
  f32x4 a0 = MFMA16(KA1, w1, z);
  a0 = MFMA16(KA2, w1, a0);
  a0 = MFMA16(KA1, w2, a0);
  f32x4 a1 = MFMA16(KB1, w1, z);
  a1 = MFMA16(KB2, w1, a1);
  a1 = MFMA16(KB1, w2, a1);
  float r0[4], r1[4];
#pragma unroll
  for (int r = 0; r < 4; ++r) {
    r0[r] = hm + LOG2FD(a0[r]);
    r1[r] = hm + LOG2FD(a1[r]);
  }
  if (CHECKED) {
    float mn = fminf(fminf(fminf(a0[0], a0[1]), fminf(a0[2], a0[3])),
                     fminf(fminf(a1[0], a1[1]), fminf(a1[2], a1[3])));
    if (__any(mn < T1F)) {
      float wb[8];
#pragma unroll
      for (int e = 0; e < 8; ++e) wb[e] = EXP2F(d[e] + 96.f);
      bf16x8 u1, u2;
      split_pack(wb, u1, u2);
      f32x4 b0 = MFMA16(KA1, u1, z);
      b0 = MFMA16(KA2, u1, b0);
      b0 = MFMA16(KA1, u2, b0);
      f32x4 b1 = MFMA16(KB1, u1, z);
      b1 = MFMA16(KB2, u1, b1);
      b1 = MFMA16(KB1, u2, b1);
      bool mybad = false;
#pragma unroll
      for (int r = 0; r < 4; ++r) {
        if (a0[r] < T1F) r0[r] = (hm - 96.f) + LOG2FD(b0[r]);
        if (a1[r] < T1F) r1[r] = (hm - 96.f) + LOG2FD(b1[r]);
        mybad |= (a0[r] < T1F) && (b0[r] < T1F);
        mybad |= (a1[r] < T1F) && (b1[r] < T1F);
      }
      if (__any(mybad)) {   // beyond 192: exact per-row fixup (very rare)
        float4 h0 = {H[0], H[1], H[2], H[3]};
        float4 h1 = {H[4], H[5], H[6], H[7]};
        *(float4*)&Hdump[b15*36 + 8*g]     = h0;
        *(float4*)&Hdump[b15*36 + 8*g + 4] = h1;
        asm volatile("" ::: "memory");
        const float* HB = &Hdump[b15*36];
#pragma unroll
        for (int r = 0; r < 4; ++r) {
          if ((a0[r] < T1F) && (b0[r] < T1F)) r0[r] = exact_lse(pos2, HB, 4*g + r, inv);
          if ((a1[r] < T1F) && (b1[r] < T1F)) r1[r] = exact_lse(pos2, HB, 16 + 4*g + r, inv);
        }
      }
    }
  }
  float4 v0 = {nde*r0[0], nde*r0[1], nde*r0[2], nde*r0[3]};
  float4 v1 = {nde*r1[0], nde*r1[1], nde*r1[2], nde*r1[3]};
  *(float4*)&Ts[b15*36 + 4*g]      = v0;   // D-layout: batch b15, rows 4g+r
  *(float4*)&Ts[b15*36 + 4*g + 16] = v1;   // rows 16+4g+r
}

template<bool CHECKED>
__device__ __forceinline__ void p_iter(P1& s, float* Tw, float* Hdump,
    float inv, float nde, bool mergeFirst, int b15, int g, const float2* pos2) {
  if (mergeFirst) {
    pot_merge(s.Fba, Tw + 0*576, b15, g);
    pot_merge(s.Gab, Tw + 1*576, b15, g);
    pot_merge(s.Faa, Tw + 2*576, b15, g);
    pot_merge(s.Gbb, Tw + 3*576, b15, g);
  }
  float H[8];
#pragma unroll
  for (int e = 0; e < 8; ++e) H[e] = fmaf(s.Gab[e], inv, s.bl2[e]);
  ksoft<CHECKED>(Tw + 0*576, Hdump, H, s.KA1, s.KA2, s.KB1, s.KB2, nde, inv, b15, g, pos2);
#pragma unroll
  for (int e = 0; e < 8; ++e) H[e] = fmaf(s.Fba[e], inv, s.al2[e]);
  ksoft<CHECKED>(Tw + 1*576, Hdump, H, s.KA1, s.KA2, s.KB1, s.KB2, nde, inv, b15, g, pos2);
#pragma unroll
  for (int e = 0; e < 8; ++e) H[e] = fmaf(s.Faa[e], inv, s.al2[e]);
  ksoft<CHECKED>(Tw + 2*576, Hdump, H, s.KA1, s.KA2, s.KB1, s.KB2, nde, inv, b15, g, pos2);
#pragma unroll
  for (int e = 0; e < 8; ++e) H[e] = fmaf(s.Gbb[e], inv, s.bl2[e]);
  ksoft<CHECKED>(Tw + 3*576, Hdump, H, s.KA1, s.KA2, s.KB1, s.KB2, nde, inv, b15, g, pos2);
}

__global__ __launch_bounds__(64, 2) void sink_kernel(
    const float* __restrict__ pred, const float* __restrict__ tgt,
    const float* __restrict__ pos, float* __restrict__ ws) {
  __shared__ __align__(16) float sT[4][576];   // [slot][b*36+i] transpose buffer
  __shared__ __align__(16) float sHb[16][36];  // fallback H dump, [batch][j]

  const int lid = threadIdx.x;          // 0..63 (one wave per block)
  const int b15 = lid & 15;
  const int g   = lid >> 4;
  const int bbase = blockIdx.x * 16;    // this wave's 16 batches
  const float2* pos2 = (const float2*)pos;
  float* Tw = &sT[0][0];
  float* Hd = &sHb[0][0];

  P1 s;
  {
    const float* pr = &pred[(bbase + b15) * 32 + 8 * g];
    const float* tr = &tgt [(bbase + b15) * 32 + 8 * g];
    float4 p0 = *(const float4*)&pr[0];
    float4 p1 = *(const float4*)&pr[4];
    float4 t0 = *(const float4*)&tr[0];
    float4 t1 = *(const float4*)&tr[4];
    s.al2[0]=LOG2FD(p0.x); s.al2[1]=LOG2FD(p0.y); s.al2[2]=LOG2FD(p0.z); s.al2[3]=LOG2FD(p0.w);
    s.al2[4]=LOG2FD(p1.x); s.al2[5]=LOG2FD(p1.y); s.al2[6]=LOG2FD(p1.z); s.al2[7]=LOG2FD(p1.w);
    s.bl2[0]=LOG2FD(t0.x); s.bl2[1]=LOG2FD(t0.y); s.bl2[2]=LOG2FD(t0.z); s.bl2[3]=LOG2FD(t0.w);
    s.bl2[4]=LOG2FD(t1.x); s.bl2[5]=LOG2FD(t1.y); s.bl2[6]=LOG2FD(t1.z); s.bl2[7]=LOG2FD(t1.w);
  }
  float c2a[8], c2b[8];   // C*log2e rows b15 and b15+16, cols j=8g+e (A-layout)
  {
    float2 pm0 = pos2[b15];
    float2 pm1 = pos2[b15 + 16];
#pragma unroll
    for (int e = 0; e < 8; ++e) {
      float2 pj = pos2[8*g + e];
      float dx0 = pm0.x - pj.x, dy0 = pm0.y - pj.y;
      float dx1 = pm1.x - pj.x, dy1 = pm1.y - pj.y;
      c2a[e] = (0.5f*L2E)*(dx0*dx0 + dy0*dy0);
      c2b[e] = (0.5f*L2E)*(dx1*dx1 + dy1*dy1);
    }
  }

  // ---- init at eps0 = 8 ----
  buildK(c2a, c2b, 0.125f, s.KA1, s.KA2, s.KB1, s.KB2);
  ksoft<false>(Tw + 1*576, Hd, s.al2, s.KA1, s.KA2, s.KB1, s.KB2, -8.f/9.f, 0.125f, b15, g, pos2);
  ksoft<false>(Tw + 0*576, Hd, s.bl2, s.KA1, s.KA2, s.KB1, s.KB2, -8.f/9.f, 0.125f, b15, g, pos2);
  pot_assign(s.Gab, Tw + 1*576, b15, g);
  pot_assign(s.Fba, Tw + 0*576, b15, g);
#pragma unroll
  for (int e = 0; e < 8; ++e) { s.Faa[e] = s.Gab[e]; s.Gbb[e] = s.Fba[e]; }

  // ---- eps schedule [8, 8, 2, 0.5, 0.125, 0.03125, 0.01], deferred averaging ----
  p_iter<false>(s, Tw, Hd, 0.125f, -8.f/9.f, false, b15, g, pos2);   // eps=8
  p_iter<false>(s, Tw, Hd, 0.125f, -8.f/9.f, true,  b15, g, pos2);   // eps=8
  buildK(c2a, c2b, 0.5f, s.KA1, s.KA2, s.KB1, s.KB2);
  p_iter<false>(s, Tw, Hd, 0.5f, -2.f/3.f, true, b15, g, pos2);      // eps=2
  buildK(c2a, c2b, 2.f, s.KA1, s.KA2, s.KB1, s.KB2);
  p_iter<false>(s, Tw, Hd, 2.f, -1.f/3.f, true, b15, g, pos2);       // eps=0.5
  buildK(c2a, c2b, 8.f, s.KA1, s.KA2, s.KB1, s.KB2);
  p_iter<false>(s, Tw, Hd, 8.f, -1.f/9.f, true, b15, g, pos2);       // eps=0.125
  buildK(c2a, c2b, 32.f, s.KA1, s.KA2, s.KB1, s.KB2);
  p_iter<true>(s, Tw, Hd, 32.f, -1.f/33.f, true, b15, g, pos2);      // eps=0.03125
  buildK(c2a, c2b, 100.f, s.KA1, s.KA2, s.KB1, s.KB2);
  p_iter<true>(s, Tw, Hd, 100.f, -1.f/101.f, true, b15, g, pos2);    // eps=0.01

  // ---- final extrapolation at eps=0.01: merge, compute, assign ----
  pot_merge(s.Fba, Tw + 0*576, b15, g);
  pot_merge(s.Gab, Tw + 1*576, b15, g);
  pot_merge(s.Faa, Tw + 2*576, b15, g);
  pot_merge(s.Gbb, Tw + 3*576, b15, g);
  {
    float H[8];
#pragma unroll
    for (int e = 0; e < 8; ++e) H[e] = fmaf(s.Gab[e], 100.f, s.bl2[e]);
    ksoft<true>(Tw + 0*576, Hd, H, s.KA1, s.KA2, s.KB1, s.KB2, -1.f/101.f, 100.f, b15, g, pos2);
#pragma unroll
    for (int e = 0; e < 8; ++e) H[e] = fmaf(s.Fba[e], 100.f, s.al2[e]);
    ksoft<true>(Tw + 1*576, Hd, H, s.KA1, s.KA2, s.KB1, s.KB2, -1.f/101.f, 100.f, b15, g, pos2);
#pragma unroll
    for (int e = 0; e < 8; ++e) H[e] = fmaf(s.Faa[e], 100.f, s.al2[e]);
    ksoft<true>(Tw + 2*576, Hd, H, s.KA1, s.KA2, s.KB1, s.KB2, -1.f/101.f, 100.f, b15, g, pos2);
#pragma unroll
    for (int e = 0; e < 8; ++e) H[e] = fmaf(s.Gbb[e], 100.f, s.bl2[e]);
    ksoft<true>(Tw + 3*576, Hd, H, s.KA1, s.KA2, s.KB1, s.KB2, -1.f/101.f, 100.f, b15, g, pos2);
  }
  pot_assign(s.Fba, Tw + 0*576, b15, g);
  pot_assign(s.Gab, Tw + 1*576, b15, g);
  pot_assign(s.Faa, Tw + 2*576, b15, g);
  pot_assign(s.Gbb, Tw + 3*576, b15, g);

  // ---- loss: per-lane partial over its 8 (batch b15, j) entries ----
  float c = 0.f;
#pragma unroll
  for (int e = 0; e < 8; ++e) {
    c += EXP2F(s.al2[e]) * (EXP2F(-s.Faa[e]) - EXP2F(-s.Fba[e]))
       + EXP2F(s.bl2[e]) * (EXP2F(-s.Gbb[e]) - EXP2F(-s.Gab[e]));
  }
  c += __shfl_xor(c, 1);
  c += __shfl_xor(c, 2);
  c += __shfl_xor(c, 4);
  c += __shfl_xor(c, 8);
  c += __shfl_xor(c, 16);
  c += __shfl_xor(c, 32);
  if (lid == 0) ws[blockIdx.x] = c;
}

__global__ __launch_bounds__(256) void reduce_kernel(
    const float* __restrict__ ws, float* __restrict__ out, int n, float scale) {
  float s = 0.f;
  for (int i = threadIdx.x; i < n; i += 256) s += ws[i];
  s += __shfl_xor(s, 32);
  s += __shfl_xor(s, 16);
  s += __shfl_xor(s, 8);
  s += __shfl_xor(s, 4);
  s += __shfl_xor(s, 2);
  s += __shfl_xor(s, 1);
  __shared__ float a[4];
  if ((threadIdx.x & 63) == 0) a[threadIdx.x >> 6] = s;
  __syncthreads();
  if (threadIdx.x == 0) out[0] = ((a[0] + a[1]) + (a[2] + a[3])) * scale;
}

extern "C" void kernel_launch(void* const* d_in, const int* in_sizes, int n_in,
                              void* d_out, int out_size, void* d_ws, size_t ws_size,
                              hipStream_t stream) {
  const float* pred = (const float*)d_in[0];
  const float* tgt  = (const float*)d_in[1];
  const float* pos  = (const float*)d_in[2];
  const int B = in_sizes[0] / 32;        // 32768 batches
  const int nblocks = B / 16;            // 16 batches per 64-thread wave = 2048
  float* ws = (float*)d_ws;

  sink_kernel<<<nblocks, 64, 0, stream>>>(pred, tgt, pos, ws);
  reduce_kernel<<<1, 256, 0, stream>>>(ws, (float*)d_out, nblocks,
                                       1.005f / (float)B);
}